// Round 2
// baseline (890.193 us; speedup 1.0000x reference)
//
#include <hip/hip_runtime.h>
#include <math.h>

#define IN_DIM 128
#define HID 64
#define OUTD 32

// ---------------- degree ----------------

__global__ void k_zero_deg(int* __restrict__ deg, int n) {
    int i = blockIdx.x * blockDim.x + threadIdx.x;
    if (i < n) deg[i] = 0;  // in-degree only; self-loop handled analytically
}

__global__ void k_scatter_deg(const int* __restrict__ dst, int* __restrict__ deg, int e) {
    int i = blockIdx.x * blockDim.x + threadIdx.x;
    if (i < e) atomicAdd(&deg[dst[i]], 1);
}

// ---------------- CSR build ----------------
// Single-block exclusive scan of deg -> rowptr (and cursor copy), plus
// dinv = rsqrt(deg+1), plus zeroing the column-stats buffer for this graph.
__global__ void k_scan_csr(const int* __restrict__ deg, int* __restrict__ rowptr,
                           int* __restrict__ cur, float* __restrict__ dinv,
                           double* __restrict__ st, int n, int e) {
    __shared__ int sums[1024];
    int tid = threadIdx.x;
    int chunk = (n + 1023) / 1024;
    int lo = tid * chunk;
    int hi = lo + chunk; if (hi > n) hi = n;
    int s = 0;
    for (int i = lo; i < hi; ++i) s += deg[i];
    sums[tid] = s;
    __syncthreads();
    // Hillis-Steele inclusive scan over 1024 block sums
    for (int off = 1; off < 1024; off <<= 1) {
        int v = (tid >= off) ? sums[tid - off] : 0;
        __syncthreads();
        sums[tid] += v;
        __syncthreads();
    }
    int base = (tid == 0) ? 0 : sums[tid - 1];
    for (int i = lo; i < hi; ++i) {
        rowptr[i] = base;
        cur[i] = base;
        int d = deg[i];
        dinv[i] = rsqrtf((float)(d + 1));
        base += d;
    }
    if (tid == 0) rowptr[n] = e;
    if (tid < 64) st[tid] = 0.0;
}

__global__ void k_fill_csr(const int* __restrict__ src, const int* __restrict__ dst,
                           int* cur, int* __restrict__ csr_src, int e) {
    int i = blockIdx.x * blockDim.x + threadIdx.x;
    if (i < e) {
        int pos = atomicAdd(&cur[dst[i]], 1);
        csr_src[pos] = src[i];
    }
}

// ---------------- dense matmul: Hs[n,D] = (X[n,K] @ W[K,D]) * dinv[node] ----------------
template<int K, int D>
__global__ void k_matmul(const float* __restrict__ X, const float* __restrict__ W,
                         const float* __restrict__ dinv, float* __restrict__ H, int n) {
    constexpr int NPB = 256 / D;
    __shared__ float xs[NPB][K];
    int node0 = blockIdx.x * NPB;
    int lid = threadIdx.x;
    for (int idx = lid; idx < NPB * K; idx += 256) {
        int nn = idx / K, kk = idx % K;
        int gn = node0 + nn;
        xs[nn][kk] = (gn < n) ? X[(size_t)gn * K + kk] : 0.0f;
    }
    __syncthreads();
    int g = lid / D, f = lid % D;
    int node = node0 + g;
    if (node >= n) return;
    float acc = 0.0f;
#pragma unroll
    for (int k = 0; k < K; ++k) acc = fmaf(xs[g][k], W[k * D + f], acc);
    H[(size_t)node * D + f] = acc * dinv[node];
}

// ---------------- CSR gather aggregation ----------------
// out[d,f] = dinv[d] * ( Hs[d,f] + sum_{incoming s} Hs[s,f] )   [+ b, relu]
template<int D, bool RELU>
__global__ void k_gather(const int* __restrict__ rowptr, const int* __restrict__ csr_src,
                         const float* __restrict__ Hs, const float* __restrict__ dinv,
                         const float* __restrict__ b, float* __restrict__ out, int n) {
    constexpr int NPB = 256 / D;
    int tid = threadIdx.x;
    int f = tid & (D - 1);
    int node = blockIdx.x * NPB + tid / D;
    if (node >= n) return;
    int lo = rowptr[node], hi = rowptr[node + 1];
    float acc = Hs[(size_t)node * D + f];  // self-loop term
    for (int j = lo; j < hi; ++j) {
        int s = csr_src[j];
        acc += Hs[(size_t)s * D + f];
    }
    float v = dinv[node] * acc;
    if (RELU) v = fmaxf(v + b[f], 0.0f);
    out[(size_t)node * D + f] = v;
}

// ---------------- column z-score ----------------

__global__ void k_stats(const float* __restrict__ O, double* __restrict__ st, int n) {
    int tid = threadIdx.x;
    int c = tid & 31;
    double s = 0.0, q = 0.0;
    long total = (long)n * OUTD;
    for (long t = (long)blockIdx.x * blockDim.x + tid; t < total;
         t += (long)gridDim.x * blockDim.x) {
        double v = (double)O[t];
        s += v; q += v * v;
    }
    __shared__ double ls[256], lq[256];
    ls[tid] = s; lq[tid] = q;
    __syncthreads();
    if (tid < 32) {
        for (int j = 32; j < 256; j += 32) { s += ls[tid + j]; q += lq[tid + j]; }
        atomicAdd(&st[c], s);
        atomicAdd(&st[c + 32], q);
    }
}

__global__ void k_finalize_stats(const double* __restrict__ st, float* __restrict__ mr, int n) {
    int c = threadIdx.x;
    if (c < 32) {
        double sum = st[c], sq = st[c + 32];
        double mean = sum / (double)n;
        double var = (sq - sum * sum / (double)n) / (double)(n - 1);
        mr[c] = (float)mean;
        mr[c + 32] = (float)(1.0 / sqrt(var));
    }
}

__global__ void k_transform(float* __restrict__ O, const float* __restrict__ mr, int n) {
    int t = blockIdx.x * blockDim.x + threadIdx.x;
    if (t < n * OUTD) {
        int c = t & 31;
        O[t] = (O[t] - mr[c]) * mr[c + 32];
    }
}

// ---------------- launch ----------------

extern "C" void kernel_launch(void* const* d_in, const int* in_sizes, int n_in,
                              void* d_out, int out_size, void* d_ws, size_t ws_size,
                              hipStream_t stream) {
    const float* x1 = (const float*)d_in[0];
    const int*   ei1 = (const int*)d_in[1];
    const float* x2 = (const float*)d_in[2];
    const int*   ei2 = (const int*)d_in[3];
    const float* W1 = (const float*)d_in[4];
    const float* b1 = (const float*)d_in[5];
    const float* W2 = (const float*)d_in[6];
    const float* b2 = (const float*)d_in[7];
    (void)b2;  // column-constant shift cancels exactly in the z-score
    (void)n_in; (void)out_size; (void)ws_size;

    int n = in_sizes[0] / IN_DIM;  // 50000
    int e = in_sizes[1] / 2;       // 800000
    float* out = (float*)d_out;

    char* ws = (char*)d_ws;
    size_t off = 0;
    auto alloc = [&](size_t bytes) {
        void* p = ws + off;
        off = (off + bytes + 255) & ~(size_t)255;
        return p;
    };
    int*    deg     = (int*)alloc((size_t)n * 4);
    int*    rowptr  = (int*)alloc(((size_t)n + 1) * 4);
    int*    cur     = (int*)alloc((size_t)n * 4);
    int*    csr_src = (int*)alloc((size_t)e * 4);
    float*  dinv    = (float*)alloc((size_t)n * 4);
    float*  hs      = (float*)alloc((size_t)n * HID * 4);
    float*  agg     = (float*)alloc((size_t)n * HID * 4);
    double* st      = (double*)alloc(64 * 8);
    float*  mr      = (float*)alloc(64 * 4);

    for (int g = 0; g < 2; ++g) {
        const float* x  = g ? x2 : x1;
        const int*   ei = g ? ei2 : ei1;
        const int* srcv = ei;       // edge_index[0]
        const int* dstv = ei + e;   // edge_index[1]
        float* og = out + (size_t)g * n * OUTD;

        // CSR of incoming edges (reused by both layers)
        k_zero_deg<<<(n + 255) / 256, 256, 0, stream>>>(deg, n);
        k_scatter_deg<<<(e + 255) / 256, 256, 0, stream>>>(dstv, deg, e);
        k_scan_csr<<<1, 1024, 0, stream>>>(deg, rowptr, cur, dinv, st, n, e);
        k_fill_csr<<<(e + 255) / 256, 256, 0, stream>>>(srcv, dstv, cur, csr_src, e);

        // layer 1: Hs = (x@W1)*dinv ; agg = relu(dinv*(Hs[d] + sum Hs[s]) + b1)
        k_matmul<IN_DIM, HID><<<(n + 3) / 4, 256, 0, stream>>>(x, W1, dinv, hs, n);
        k_gather<HID, true><<<(n + 3) / 4, 256, 0, stream>>>(rowptr, csr_src, hs, dinv, b1, agg, n);

        // layer 2 straight into output slab (b2 cancels in z-score)
        k_matmul<HID, OUTD><<<(n + 7) / 8, 256, 0, stream>>>(agg, W2, dinv, hs, n);
        k_gather<OUTD, false><<<(n + 7) / 8, 256, 0, stream>>>(rowptr, csr_src, hs, dinv, b1, og, n);

        // z-score columns (st zeroed inside k_scan_csr)
        k_stats<<<1024, 256, 0, stream>>>(og, st, n);
        k_finalize_stats<<<1, 32, 0, stream>>>(st, mr, n);
        k_transform<<<((size_t)n * OUTD + 255) / 256, 256, 0, stream>>>(og, mr, n);
    }
}

// Round 3
// 607.810 us; speedup vs baseline: 1.4646x; 1.4646x over previous
//
#include <hip/hip_runtime.h>
#include <math.h>

#define IN_DIM 128
#define HID 64
#define OUTD 32

// Per-graph pointer bundle for kernels fused across both graphs (blockIdx.y).
struct GB {
    const int* src; const int* dst;
    int* deg; int* rowptr; int* cur; int* csr_src;
    int* bsum; int* boff;
    float* dinv;
    double* st; float* mr; float* og;
};

// ---------------- degree ----------------

__global__ void k_scatter_deg(GB g0, GB g1, int e) {
    const GB& g = blockIdx.y ? g1 : g0;
    int i = blockIdx.x * 256 + threadIdx.x;
    if (i < e) atomicAdd(&g.deg[g.dst[i]], 1);
}

// ---------------- parallel CSR scan (3 stages) ----------------

__global__ void k_partial(GB g0, GB g1, int n) {
    const GB& g = blockIdx.y ? g1 : g0;
    int i = blockIdx.x * 256 + threadIdx.x;
    int v = (i < n) ? g.deg[i] : 0;
#pragma unroll
    for (int off = 32; off > 0; off >>= 1) v += __shfl_down(v, off, 64);
    __shared__ int ls[4];
    if ((threadIdx.x & 63) == 0) ls[threadIdx.x >> 6] = v;
    __syncthreads();
    if (threadIdx.x == 0) g.bsum[blockIdx.x] = ls[0] + ls[1] + ls[2] + ls[3];
}

// one block per graph; nb <= 1024
__global__ void k_scan_bsums(GB g0, GB g1, int nb) {
    const GB& g = blockIdx.y ? g1 : g0;
    __shared__ int ls[1024];
    int tid = threadIdx.x;
    int v = (tid < nb) ? g.bsum[tid] : 0;
    ls[tid] = v;
    __syncthreads();
    for (int off = 1; off < 1024; off <<= 1) {
        int u = (tid >= off) ? ls[tid - off] : 0;
        __syncthreads();
        ls[tid] += u;
        __syncthreads();
    }
    if (tid < nb) g.boff[tid] = ls[tid] - v;  // exclusive
}

__global__ void k_emit(GB g0, GB g1, int n, int e) {
    const GB& g = blockIdx.y ? g1 : g0;
    __shared__ int ls[256];
    int tid = threadIdx.x;
    int i = blockIdx.x * 256 + tid;
    int d = (i < n) ? g.deg[i] : 0;
    ls[tid] = d;
    __syncthreads();
    for (int off = 1; off < 256; off <<= 1) {
        int u = (tid >= off) ? ls[tid - off] : 0;
        __syncthreads();
        ls[tid] += u;
        __syncthreads();
    }
    int excl = ls[tid] - d + g.boff[blockIdx.x];
    if (i < n) {
        g.rowptr[i] = excl;
        g.cur[i] = excl;
        g.dinv[i] = rsqrtf((float)(d + 1));  // +1 = self-loop
        if (i == n - 1) g.rowptr[n] = e;
    }
}

__global__ void k_fill(GB g0, GB g1, int e) {
    const GB& g = blockIdx.y ? g1 : g0;
    int i = blockIdx.x * 256 + threadIdx.x;
    if (i < e) {
        int pos = atomicAdd(&g.cur[g.dst[i]], 1);
        g.csr_src[pos] = g.src[i];
    }
}

// ---------------- dense matmul: Hs[n,D] = (X[n,K] @ W[K,D]) * dinv ----------------

template<int K, int D>
__global__ void k_matmul(const float* __restrict__ X, const float* __restrict__ W,
                         const float* __restrict__ dinv, float* __restrict__ H, int n) {
    constexpr int NPB = 256 / D;
    __shared__ float xs[NPB][K];
    int node0 = blockIdx.x * NPB;
    int lid = threadIdx.x;
    for (int idx = lid; idx < NPB * K; idx += 256) {
        int nn = idx / K, kk = idx % K;
        int gn = node0 + nn;
        xs[nn][kk] = (gn < n) ? X[(size_t)gn * K + kk] : 0.0f;
    }
    __syncthreads();
    int g = lid / D, f = lid % D;
    int node = node0 + g;
    if (node >= n) return;
    float acc = 0.0f;
#pragma unroll
    for (int k = 0; k < K; ++k) acc = fmaf(xs[g][k], W[k * D + f], acc);
    H[(size_t)node * D + f] = acc * dinv[node];
}

// ---------------- CSR gather: out[d,f] = dinv[d]*(Hs[d,f]+sum Hs[s,f]) [+b,relu] ----------------

template<int D, bool RELU>
__global__ void k_gather(const int* __restrict__ rowptr, const int* __restrict__ csr_src,
                         const float* __restrict__ Hs, const float* __restrict__ dinv,
                         const float* __restrict__ b, float* __restrict__ out, int n) {
    constexpr int NPB = 256 / D;
    int tid = threadIdx.x;
    int f = tid & (D - 1);
    int node = blockIdx.x * NPB + tid / D;
    if (node >= n) return;
    int lo = rowptr[node], hi = rowptr[node + 1];
    float acc = Hs[(size_t)node * D + f];  // self-loop
    for (int j = lo; j < hi; ++j) {
        int s = csr_src[j];
        acc += Hs[(size_t)s * D + f];
    }
    float v = dinv[node] * acc;
    if (RELU) v = fmaxf(v + b[f], 0.0f);
    out[(size_t)node * D + f] = v;
}

// ---------------- column z-score ----------------

__global__ void k_stats(GB g0, GB g1, int n) {
    const GB& g = blockIdx.y ? g1 : g0;
    int tid = threadIdx.x;
    int c = tid & 31;
    double s = 0.0, q = 0.0;
    long total = (long)n * OUTD;
    for (long t = (long)blockIdx.x * blockDim.x + tid; t < total;
         t += (long)gridDim.x * blockDim.x) {
        double v = (double)g.og[t];
        s += v; q += v * v;
    }
    __shared__ double ls[256], lq[256];
    ls[tid] = s; lq[tid] = q;
    __syncthreads();
    if (tid < 32) {
        for (int j = 32; j < 256; j += 32) { s += ls[tid + j]; q += lq[tid + j]; }
        atomicAdd(&g.st[c], s);
        atomicAdd(&g.st[c + 32], q);
    }
}

__global__ void k_finalize(GB g0, GB g1, int n) {
    const GB& g = blockIdx.y ? g1 : g0;
    int c = threadIdx.x;
    if (c < 32) {
        double sum = g.st[c], sq = g.st[c + 32];
        double mean = sum / (double)n;
        double var = (sq - sum * sum / (double)n) / (double)(n - 1);
        g.mr[c] = (float)mean;
        g.mr[c + 32] = (float)(1.0 / sqrt(var));
    }
}

__global__ void k_transform(GB g0, GB g1, int n) {
    const GB& g = blockIdx.y ? g1 : g0;
    int t = blockIdx.x * 256 + threadIdx.x;
    if (t < n * OUTD) {
        int c = t & 31;
        g.og[t] = (g.og[t] - g.mr[c]) * g.mr[c + 32];
    }
}

// ---------------- launch ----------------

extern "C" void kernel_launch(void* const* d_in, const int* in_sizes, int n_in,
                              void* d_out, int out_size, void* d_ws, size_t ws_size,
                              hipStream_t stream) {
    const float* x1 = (const float*)d_in[0];
    const int*   ei1 = (const int*)d_in[1];
    const float* x2 = (const float*)d_in[2];
    const int*   ei2 = (const int*)d_in[3];
    const float* W1 = (const float*)d_in[4];
    const float* b1 = (const float*)d_in[5];
    const float* W2 = (const float*)d_in[6];
    const float* b2 = (const float*)d_in[7];
    (void)b2;  // column-constant shift cancels exactly in the z-score
    (void)n_in; (void)out_size; (void)ws_size;

    int n = in_sizes[0] / IN_DIM;  // 50000
    int e = in_sizes[1] / 2;       // 800000
    float* out = (float*)d_out;
    int nb  = (n + 255) / 256;     // 196
    int nbe = (e + 255) / 256;     // 3125

    char* ws = (char*)d_ws;
    size_t off = 0;
    auto alloc = [&](size_t bytes) {
        void* p = ws + off;
        off = (off + bytes + 255) & ~(size_t)255;
        return p;
    };
    int*    deg_base = (int*)alloc((size_t)2 * n * 4);      // both graphs contiguous (one memset)
    double* st_base  = (double*)alloc(2 * 64 * 8);          // both graphs contiguous (one memset)
    float*  hs       = (float*)alloc((size_t)n * HID * 4);  // shared across graphs (serial compute)
    float*  agg      = (float*)alloc((size_t)n * HID * 4);

    GB G[2];
    for (int g = 0; g < 2; ++g) {
        const int* ei = g ? ei2 : ei1;
        G[g].src = ei;
        G[g].dst = ei + e;
        G[g].deg = deg_base + (size_t)g * n;
        G[g].st  = st_base + (size_t)g * 64;
        G[g].rowptr  = (int*)alloc(((size_t)n + 1) * 4);
        G[g].cur     = (int*)alloc((size_t)n * 4);
        G[g].csr_src = (int*)alloc((size_t)e * 4);
        G[g].bsum    = (int*)alloc((size_t)nb * 4);
        G[g].boff    = (int*)alloc((size_t)nb * 4);
        G[g].dinv    = (float*)alloc((size_t)n * 4);
        G[g].mr      = (float*)alloc(64 * 4);
        G[g].og      = out + (size_t)g * n * OUTD;
    }

    hipMemsetAsync(deg_base, 0, (size_t)2 * n * 4, stream);
    hipMemsetAsync(st_base, 0, 2 * 64 * sizeof(double), stream);

    // fused CSR build for both graphs
    k_scatter_deg<<<dim3(nbe, 2), 256, 0, stream>>>(G[0], G[1], e);
    k_partial<<<dim3(nb, 2), 256, 0, stream>>>(G[0], G[1], n);
    k_scan_bsums<<<dim3(1, 2), 1024, 0, stream>>>(G[0], G[1], nb);
    k_emit<<<dim3(nb, 2), 256, 0, stream>>>(G[0], G[1], n, e);
    k_fill<<<dim3(nbe, 2), 256, 0, stream>>>(G[0], G[1], e);

    // per-graph compute (hs/agg shared -> serialize)
    for (int g = 0; g < 2; ++g) {
        const float* x = g ? x2 : x1;
        k_matmul<IN_DIM, HID><<<(n + 3) / 4, 256, 0, stream>>>(x, W1, G[g].dinv, hs, n);
        k_gather<HID, true><<<(n + 3) / 4, 256, 0, stream>>>(G[g].rowptr, G[g].csr_src, hs,
                                                             G[g].dinv, b1, agg, n);
        k_matmul<HID, OUTD><<<(n + 7) / 8, 256, 0, stream>>>(agg, W2, G[g].dinv, hs, n);
        k_gather<OUTD, false><<<(n + 7) / 8, 256, 0, stream>>>(G[g].rowptr, G[g].csr_src, hs,
                                                               G[g].dinv, b1, G[g].og, n);
    }

    // fused z-score for both graphs
    k_stats<<<dim3(512, 2), 256, 0, stream>>>(G[0], G[1], n);
    k_finalize<<<dim3(1, 2), 32, 0, stream>>>(G[0], G[1], n);
    k_transform<<<dim3((n * OUTD + 255) / 256, 2), 256, 0, stream>>>(G[0], G[1], n);
}